// Round 4
// baseline (972.093 us; speedup 1.0000x reference)
//
#include <hip/hip_runtime.h>

#define B_ 4096
#define S_ 2048

__device__ __forceinline__ float rcp_(float x)  { return __builtin_amdgcn_rcpf(x); }
__device__ __forceinline__ float exp2_(float x) { return __builtin_amdgcn_exp2f(x); }
// sigmoid(x) = 1/(1+2^(-x*log2e));  tanh(x) = 1 - 2/(1+2^(2x*log2e))
// both saturate cleanly at +-inf — no NaN possible
__device__ __forceinline__ float tanh_(float x) {
    return fmaf(-2.0f, rcp_(1.0f + exp2_(2.88539008f * x)), 1.0f);
}

// DPP cross-lane (VALU ~2cyc; replaces 120cyc ds_bpermute). row_ror:n = 0x120+n.
template<int CTRL>
__device__ __forceinline__ float dppf(float x) {
    int v = __builtin_bit_cast(int, x);
    return __builtin_bit_cast(float,
        __builtin_amdgcn_update_dpp(v, v, CTRL, 0xF, 0xF, false));
}
#define ROR1f dppf<0x121>
#define ROR8f dppf<0x128>
__device__ __forceinline__ int dppi_ror1(int x) {
    return __builtin_amdgcn_update_dpp(x, x, 0x121, 0xF, 0xF, false);
}

__device__ __forceinline__ void ld8(const float* p, float* o) {
    float4 a = *(const float4*)p;
    float4 b = *(const float4*)(p + 4);
    o[0] = a.x; o[1] = a.y; o[2] = a.z; o[3] = a.w;
    o[4] = b.x; o[5] = b.y; o[6] = b.z; o[7] = b.w;
}

// 16 lanes per batch element; 4 elements/wave; 1024 waves = 1 wave/SIMD.
// Software-pipelined: body(t) = [L0(t) tail || L1(t-1) tail] (independent given
// h0(t-1),h1(t-2) state) then the 6 fused dot-chains for L1(t) & L0(t+1), which
// SHARE the h0 DPP rotation stream. x prefetched 4 steps ahead (4 buffers).
__global__ __launch_bounds__(64, 1) void lstm_main(
    const float* __restrict__ seq, const int* __restrict__ lengths,
    const float* __restrict__ Wih0, const float* __restrict__ Whh0,
    const float* __restrict__ bih0, const float* __restrict__ bhh0,
    const float* __restrict__ Wih1, const float* __restrict__ Whh1,
    const float* __restrict__ bih1, const float* __restrict__ bhh1,
    const float* __restrict__ Wl, const float* __restrict__ bl,
    const float* __restrict__ Wv, const float* __restrict__ bv,
    const float* __restrict__ Wa, const float* __restrict__ ba,
    const float* __restrict__ lstd, float* __restrict__ out)
{
    const int tid  = threadIdx.x;
    const int grp  = tid >> 4;
    const int sub  = tid & 15;
    const int j    = sub & 7;
    const int half = sub >> 3;
    const int b    = blockIdx.x * 4 + grp;
    const int base = tid & 48;

    const int gA = half * 8 + j;          // i or f row
    const int gB = 16 + half * 8 + j;     // g~ or o row

    // discover DPP ror:1 direction at runtime (affects only setup indexing)
    const int probe = dppi_ror1(sub);
    const int delta = (sub - probe) & 7;

    float wi0A[8], wi0B[8];
    ld8(Wih0 + gA * 8, wi0A);
    ld8(Wih0 + gB * 8, wi0B);
    float wh0A[8], wh0B[8], wi1A[8], wi1B[8], wh1A[8], wh1B[8];
    {
        int idx = j;
        #pragma unroll
        for (int k = 0; k < 8; ++k) {
            wh0A[k] = Whh0[gA * 8 + idx];
            wh0B[k] = Whh0[gB * 8 + idx];
            wi1A[k] = Wih1[gA * 8 + idx];
            wi1B[k] = Wih1[gB * 8 + idx];
            wh1A[k] = Whh1[gA * 8 + idx];
            wh1B[k] = Whh1[gB * 8 + idx];
            idx = (idx - delta) & 7;
        }
    }
    const float bs0A = bih0[gA] + bhh0[gA];
    const float bs0B = bih0[gB] + bhh0[gB];
    const float bs1A = bih1[gA] + bhh1[gA];
    const float bs1B = bih1[gB] + bhh1[gB];

    const float sB = half ? -1.44269504f : 2.88539008f;
    const float aB = half ?  1.0f        : -2.0f;
    const float cB = half ?  0.0f        :  1.0f;

    const int len = lengths[b];
    const int lenm1 = len - 1;
    int maxlen = len;
    maxlen = max(maxlen, __shfl_xor(maxlen, 16));
    maxlen = max(maxlen, __shfl_xor(maxlen, 32));

    float h0 = 0.0f, h1 = 0.0f, c0 = 0.0f, c1 = 0.0f, ysave = 0.0f;

    const float* xbase = seq + (size_t)b * S_ * 8;
    // x(0) for prologue gates; xb0..xb3 = x(1..4)
    float xt[8], xb0[8], xb1[8], xb2[8], xb3[8];
    ld8(xbase,      xt);
    ld8(xbase + 8,  xb0);
    ld8(xbase + 16, xb1);
    ld8(xbase + 24, xb2);
    ld8(xbase + 32, xb3);

    // prologue: L0(0) gate pre-acts (h0=0 -> x-part + bias only)
    float g0A = bs0A, g0B = bs0B;
    #pragma unroll
    for (int k = 0; k < 8; ++k) {
        g0A = fmaf(wi0A[k], xt[k], g0A);
        g0B = fmaf(wi0B[k], xt[k], g0B);
    }
    // L1(-1) gates: sigmoid(-40)=0 kills i*g -> c1 stays 0, tanh(0)=0 -> h1=0
    float G1A = -40.0f, G1B = 0.0f;

    // body: step t. Consumes g0A/g0B (L0(t) gates), G1A/G1B (L1(t-1) gates),
    // xu = x(t+1); produces next g0*/G1*; loads x(t+5) into xl.
    auto body = [&](const float* xu, float* xl, int t) {
        // ---- tails: L0(t) || L1(t-1), fully independent ----
        float vA0 = rcp_(1.0f + exp2_(-1.44269504f * g0A));
        float vA1 = rcp_(1.0f + exp2_(-1.44269504f * G1A));
        float vB0 = fmaf(aB, rcp_(1.0f + exp2_(sB * g0B)), cB);
        float vB1 = fmaf(aB, rcp_(1.0f + exp2_(sB * G1B)), cB);
        float xA0 = ROR8f(vA0), xB0 = ROR8f(vB0);
        float xA1 = ROR8f(vA1), xB1 = ROR8f(vB1);
        float i0 = half ? xA0 : vA0, f0 = half ? vA0 : xA0;
        float g0 = half ? xB0 : vB0, o0 = half ? vB0 : xB0;
        float i1 = half ? xA1 : vA1, f1 = half ? vA1 : xA1;
        float g1 = half ? xB1 : vB1, o1 = half ? vB1 : xB1;
        c0 = fmaf(f0, c0, i0 * g0);
        c1 = fmaf(f1, c1, i1 * g1);
        h0 = o0 * tanh_(c0);
        float h1n = o1 * tanh_(c1);
        h1 = h1n;
        ysave = ((t - 1) == lenm1) ? h1n : ysave;   // h1(t-1) capture

        // ---- dots: L1(t) and L0(t+1), shared h0 rotation stream ----
        float nA = bs0A, nB = bs0B;
        #pragma unroll
        for (int k = 0; k < 8; ++k) {
            nA = fmaf(wi0A[k], xu[k], nA);
            nB = fmaf(wi0B[k], xu[k], nB);
        }
        float a1 = bs1A, b1 = bs1B, a2 = 0.0f, b2 = 0.0f;
        float hA = 0.0f, hB = 0.0f;
        float r0 = h0, r1 = h1;
        #pragma unroll
        for (int k = 0; k < 8; ++k) {
            a1 = fmaf(wi1A[k], r0, a1);
            b1 = fmaf(wi1B[k], r0, b1);
            hA = fmaf(wh0A[k], r0, hA);
            hB = fmaf(wh0B[k], r0, hB);
            a2 = fmaf(wh1A[k], r1, a2);
            b2 = fmaf(wh1B[k], r1, b2);
            if (k < 7) { r0 = ROR1f(r0); r1 = ROR1f(r1); }
        }
        g0A = nA + hA; g0B = nB + hB;
        G1A = a1 + a2; G1B = b1 + b2;

        // prefetch x(t+5) into the buffer just consumed (next use: 4 steps away)
        ld8(xbase + (size_t)min(t + 5, S_ - 1) * 8, xl);
    };

    int t = 0;
    for (; t < maxlen; t += 4) {
        body(xb0, xb0, t);
        body(xb1, xb1, t + 1);
        body(xb2, xb2, t + 2);
        body(xb3, xb3, t + 3);
    }
    // final pending L1 tail: h1(t_exit-1); fires only for lenm1 == t_exit-1
    {
        float vA1 = rcp_(1.0f + exp2_(-1.44269504f * G1A));
        float vB1 = fmaf(aB, rcp_(1.0f + exp2_(sB * G1B)), cB);
        float xA1 = ROR8f(vA1), xB1 = ROR8f(vB1);
        float i1 = half ? xA1 : vA1, f1 = half ? vA1 : xA1;
        float g1 = half ? xB1 : vB1, o1 = half ? vB1 : xB1;
        c1 = fmaf(f1, c1, i1 * g1);
        float h1n = o1 * tanh_(c1);
        ysave = ((t - 1) == lenm1) ? h1n : ysave;
    }

    // ---- fused heads (once, off the hot loop) ----
    float yv[8];
    #pragma unroll
    for (int k = 0; k < 8; ++k) yv[k] = __shfl(ysave, base + k);
    if (sub == 0) {
        float feat[4];
        #pragma unroll
        for (int l = 0; l < 4; ++l) {
            float acc = bl[l];
            #pragma unroll
            for (int k = 0; k < 8; ++k) acc = fmaf(Wl[l * 8 + k], yv[k], acc);
            feat[l] = tanh_(acc);
        }
        float val = bv[0];
        #pragma unroll
        for (int l = 0; l < 4; ++l) val = fmaf(Wv[l], feat[l], val);
        out[b] = val;                                          // value
        #pragma unroll
        for (int a = 0; a < 4; ++a) {
            float am = ba[a];
            #pragma unroll
            for (int l = 0; l < 4; ++l) am = fmaf(Wa[a * 4 + l], feat[l], am);
            out[4096  + b * 4 + a] = am;                       // action_mean
            float ls = lstd[a];
            out[20480 + b * 4 + a] = ls;                       // action_log_std
            out[36864 + b * 4 + a] = exp2_(1.44269504f * ls);  // action_std
        }
    }
}

extern "C" void kernel_launch(void* const* d_in, const int* in_sizes, int n_in,
                              void* d_out, int out_size, void* d_ws, size_t ws_size,
                              hipStream_t stream)
{
    const float* seq   = (const float*)d_in[0];
    const int* lengths = (const int*)d_in[1];
    const float* Wih0  = (const float*)d_in[2];
    const float* Whh0  = (const float*)d_in[3];
    const float* bih0  = (const float*)d_in[4];
    const float* bhh0  = (const float*)d_in[5];
    const float* Wih1  = (const float*)d_in[6];
    const float* Whh1  = (const float*)d_in[7];
    const float* bih1  = (const float*)d_in[8];
    const float* bhh1  = (const float*)d_in[9];
    const float* Wl    = (const float*)d_in[10];
    const float* bl    = (const float*)d_in[11];
    const float* Wv    = (const float*)d_in[12];
    const float* bv    = (const float*)d_in[13];
    const float* Wa    = (const float*)d_in[14];
    const float* ba    = (const float*)d_in[15];
    const float* lstd  = (const float*)d_in[16];

    lstm_main<<<B_ / 4, 64, 0, stream>>>(seq, lengths, Wih0, Whh0, bih0, bhh0,
                                         Wih1, Whh1, bih1, bhh1,
                                         Wl, bl, Wv, bv, Wa, ba, lstd,
                                         (float*)d_out);
}

// Round 5
// 852.659 us; speedup vs baseline: 1.1401x; 1.1401x over previous
//
#include <hip/hip_runtime.h>

#define B_ 4096
#define S_ 2048
#define CH 8          // steps per pipeline chunk (ring depth)

typedef float v2f __attribute__((ext_vector_type(2)));

__device__ __forceinline__ float rcp_(float x)  { return __builtin_amdgcn_rcpf(x); }
__device__ __forceinline__ float exp2_(float x) { return __builtin_amdgcn_exp2f(x); }
// sigmoid(x)=1/(1+2^(-x*log2e)); tanh(x)=1-2/(1+2^(2x*log2e)) — saturate clean, no NaN
__device__ __forceinline__ float tanh_(float x) {
    return fmaf(-2.0f, rcp_(1.0f + exp2_(2.88539008f * x)), 1.0f);
}
// DPP cross-lane (VALU ~2cyc). row_ror:n = 0x120+n (within 16-lane rows).
template<int CTRL>
__device__ __forceinline__ float dppf(float x) {
    int v = __builtin_bit_cast(int, x);
    return __builtin_bit_cast(float,
        __builtin_amdgcn_update_dpp(v, v, CTRL, 0xF, 0xF, false));
}
#define ROR1f dppf<0x121>
#define ROR8f dppf<0x128>
__device__ __forceinline__ int dppi_ror1(int x) {
    return __builtin_amdgcn_update_dpp(x, x, 0x121, 0xF, 0xF, false);
}
__device__ __forceinline__ void ld8(const float* p, float* o) {
    float4 a = *(const float4*)p;
    float4 b = *(const float4*)(p + 4);
    o[0] = a.x; o[1] = a.y; o[2] = a.z; o[3] = a.w;
    o[4] = b.x; o[5] = b.y; o[6] = b.z; o[7] = b.w;
}

// 2 waves/block, 4 elements/block (16 lanes each, same groups in both waves).
// Wave0 = layer-0 recurrence (global x in, h0 -> LDS ring).
// Wave1 = layer-1 recurrence (h0 from ring, lags one chunk) + ysave + heads.
// 2048 waves total = 2 waves/SIMD -> cross-wave latency hiding.
// Gate pair (A,B) per lane packed as float2 -> v_pk_fma_f32.
__global__ __launch_bounds__(128) void lstm_main(
    const float* __restrict__ seq, const int* __restrict__ lengths,
    const float* __restrict__ Wih0, const float* __restrict__ Whh0,
    const float* __restrict__ bih0, const float* __restrict__ bhh0,
    const float* __restrict__ Wih1, const float* __restrict__ Whh1,
    const float* __restrict__ bih1, const float* __restrict__ bhh1,
    const float* __restrict__ Wl, const float* __restrict__ bl,
    const float* __restrict__ Wv, const float* __restrict__ bv,
    const float* __restrict__ Wa, const float* __restrict__ ba,
    const float* __restrict__ lstd, float* __restrict__ out)
{
    __shared__ float ring[2][CH][32];   // [pingpong][step][grp*8+j]

    const int tid  = threadIdx.x;
    const int wv   = tid >> 6;            // 0 = L0 producer, 1 = L1 consumer
    const int l    = tid & 63;
    const int grp  = l >> 4;
    const int sub  = l & 15;
    const int j    = sub & 7;
    const int half = sub >> 3;
    const int b    = blockIdx.x * 4 + grp;
    const int base = l & 48;

    const int gA = half * 8 + j;          // i or f row
    const int gB = 16 + half * 8 + j;     // g~ or o row

    // DPP ror direction probe (setup-only indexing)
    const int probe = dppi_ror1(sub);
    const int delta = (sub - probe) & 7;

    // per-wave weight sets, A/B interleaved as float2 for pk_fma
    v2f win[8], whh[8], bias;
    if (wv == 0) {
        #pragma unroll
        for (int k = 0; k < 8; ++k)
            win[k] = (v2f){ Wih0[gA * 8 + k], Wih0[gB * 8 + k] };   // natural (x-dot)
        int idx = j;
        #pragma unroll
        for (int k = 0; k < 8; ++k) {
            whh[k] = (v2f){ Whh0[gA * 8 + idx], Whh0[gB * 8 + idx] }; // rotated (h-dot)
            idx = (idx - delta) & 7;
        }
        bias = (v2f){ bih0[gA] + bhh0[gA], bih0[gB] + bhh0[gB] };
    } else {
        int idx = j;
        #pragma unroll
        for (int k = 0; k < 8; ++k) {
            win[k] = (v2f){ Wih1[gA * 8 + idx], Wih1[gB * 8 + idx] }; // rotated (h0-dot)
            whh[k] = (v2f){ Whh1[gA * 8 + idx], Whh1[gB * 8 + idx] }; // rotated (h1-dot)
            idx = (idx - delta) & 7;
        }
        bias = (v2f){ bih1[gA] + bhh1[gA], bih1[gB] + bhh1[gB] };
    }

    // gate A always sigmoid; gate B: tanh (half0) or sigmoid (half1)
    const float sB = half ? -1.44269504f : 2.88539008f;
    const float aB = half ?  1.0f        : -2.0f;
    const float cB = half ?  0.0f        :  1.0f;

    const int len = lengths[b];
    const int lenm1 = len - 1;
    int maxlen = len;
    maxlen = max(maxlen, __shfl_xor(maxlen, 16));
    maxlen = max(maxlen, __shfl_xor(maxlen, 32));   // block-uniform (same 4 elems)
    const int nch = (maxlen + CH - 1) / CH;

    float hq = 0.0f, cq = 0.0f, ysave = 0.0f;   // h0/c0 (wv0) or h1/c1 (wv1)

    const float* xbase = seq + (size_t)b * S_ * 8;
    float xq[4][8];
    if (wv == 0) {
        ld8(xbase,      xq[0]);
        ld8(xbase + 8,  xq[1]);
        ld8(xbase + 16, xq[2]);
        ld8(xbase + 24, xq[3]);
    }

    // L0 step: gates -> h0; write h0 to ring slot; reload x(t+4)
    auto step0 = [&](int s, int t, float* bufp) {
        v2f acc = bias;
        #pragma unroll
        for (int k = 0; k < 8; ++k) {
            float xk = xq[s & 3][k];
            acc += win[k] * (v2f){xk, xk};
        }
        v2f ha = (v2f){0.0f, 0.0f};
        float r = hq;
        #pragma unroll
        for (int k = 0; k < 8; ++k) {
            ha += whh[k] * (v2f){r, r};
            if (k < 7) r = ROR1f(r);
        }
        acc += ha;
        float vA = rcp_(1.0f + exp2_(-1.44269504f * acc.x));
        float vB = fmaf(aB, rcp_(1.0f + exp2_(sB * acc.y)), cB);
        float xA = ROR8f(vA), xB = ROR8f(vB);
        float iq = half ? xA : vA, fq = half ? vA : xA;
        float gq = half ? xB : vB, oq = half ? vB : xB;
        cq = fmaf(fq, cq, iq * gq);
        hq = oq * tanh_(cq);
        if (half == 0) bufp[s * 32 + grp * 8 + j] = hq;   // 32 lanes, banks 0-31
        ld8(xbase + (size_t)min(t + 4, S_ - 1) * 8, xq[s & 3]);
    };

    // L1 step: h0 (from ring) + h1 recurrence; capture ysave at t==len-1
    auto step1 = [&](float h0in, int u) {
        v2f acc = bias;
        v2f ha = (v2f){0.0f, 0.0f};
        float r0 = h0in, r1 = hq;
        #pragma unroll
        for (int k = 0; k < 8; ++k) {
            acc += win[k] * (v2f){r0, r0};
            ha  += whh[k] * (v2f){r1, r1};
            if (k < 7) { r0 = ROR1f(r0); r1 = ROR1f(r1); }
        }
        acc += ha;
        float vA = rcp_(1.0f + exp2_(-1.44269504f * acc.x));
        float vB = fmaf(aB, rcp_(1.0f + exp2_(sB * acc.y)), cB);
        float xA = ROR8f(vA), xB = ROR8f(vB);
        float iq = half ? xA : vA, fq = half ? vA : xA;
        float gq = half ? xB : vB, oq = half ? vB : xB;
        cq = fmaf(fq, cq, iq * gq);
        hq = oq * tanh_(cq);
        ysave = (u == lenm1) ? hq : ysave;
    };

    auto consume = [&](int kc) {        // process chunk kc (already synced)
        const float* bufp = &ring[kc & 1][0][0];
        const int u0 = kc * CH;
        float hb[CH];
        #pragma unroll
        for (int s = 0; s < CH; ++s) hb[s] = bufp[s * 32 + grp * 8 + j];
        #pragma unroll
        for (int s = 0; s < CH; ++s) step1(hb[s], u0 + s);
    };

    for (int k = 0; k < nch; ++k) {
        if (wv == 0) {
            float* bufp = &ring[k & 1][0][0];
            const int t0 = k * CH;
            #pragma unroll
            for (int s = 0; s < CH; ++s) step0(s, t0 + s, bufp);
        } else if (k > 0) {
            consume(k - 1);
        }
        __syncthreads();
    }

    if (wv == 1) {
        consume(nch - 1);               // final pending chunk

        // ---- fused heads ----
        float yv[8];
        #pragma unroll
        for (int k = 0; k < 8; ++k) yv[k] = __shfl(ysave, base + k);
        if (sub == 0) {
            float feat[4];
            #pragma unroll
            for (int q = 0; q < 4; ++q) {
                float acc = bl[q];
                #pragma unroll
                for (int k = 0; k < 8; ++k) acc = fmaf(Wl[q * 8 + k], yv[k], acc);
                feat[q] = tanh_(acc);
            }
            float val = bv[0];
            #pragma unroll
            for (int q = 0; q < 4; ++q) val = fmaf(Wv[q], feat[q], val);
            out[b] = val;                                          // value
            #pragma unroll
            for (int a = 0; a < 4; ++a) {
                float am = ba[a];
                #pragma unroll
                for (int q = 0; q < 4; ++q) am = fmaf(Wa[a * 4 + q], feat[q], am);
                out[4096  + b * 4 + a] = am;                       // action_mean
                float ls = lstd[a];
                out[20480 + b * 4 + a] = ls;                       // action_log_std
                out[36864 + b * 4 + a] = exp2_(1.44269504f * ls);  // action_std
            }
        }
    }
}

extern "C" void kernel_launch(void* const* d_in, const int* in_sizes, int n_in,
                              void* d_out, int out_size, void* d_ws, size_t ws_size,
                              hipStream_t stream)
{
    const float* seq   = (const float*)d_in[0];
    const int* lengths = (const int*)d_in[1];
    const float* Wih0  = (const float*)d_in[2];
    const float* Whh0  = (const float*)d_in[3];
    const float* bih0  = (const float*)d_in[4];
    const float* bhh0  = (const float*)d_in[5];
    const float* Wih1  = (const float*)d_in[6];
    const float* Whh1  = (const float*)d_in[7];
    const float* bih1  = (const float*)d_in[8];
    const float* bhh1  = (const float*)d_in[9];
    const float* Wl    = (const float*)d_in[10];
    const float* bl    = (const float*)d_in[11];
    const float* Wv    = (const float*)d_in[12];
    const float* bv    = (const float*)d_in[13];
    const float* Wa    = (const float*)d_in[14];
    const float* ba    = (const float*)d_in[15];
    const float* lstd  = (const float*)d_in[16];

    lstm_main<<<B_ / 4, 128, 0, stream>>>(seq, lengths, Wih0, Whh0, bih0, bhh0,
                                          Wih1, Whh1, bih1, bhh1,
                                          Wl, bl, Wv, bv, Wa, ba, lstd,
                                          (float*)d_out);
}